// Round 1
// baseline (10135.355 us; speedup 1.0000x reference)
//
#include <hip/hip_runtime.h>
#include <stdint.h>

typedef __bf16 bf16x8 __attribute__((ext_vector_type(8)));
typedef float  f32x4  __attribute__((ext_vector_type(4)));

#define YSZ 33554432ull   // 32*512*2048 output elements

// workspace layout (bytes)
#define R1L_OFF 0ull
#define R2L_OFF 12582912ull
#define W2L_OFF 25165824ull
#define HR1_OFF 37748736ull
#define HR2_OFF 39845888ull
#define X2R_OFF 41943040ull
#define FLG_OFF 48234496ull
#define WS_NEED 48238592ull

// LDS layout (bytes)
#define SM_RECW 0
#define SM_XW0  98304
#define SM_XW1  131072
#define SM_RED0 147456
#define SM_RED1 150528
#define SM_HST  153600
#define SM_XST  154624
#define SM_BYTES 156160

__device__ __forceinline__ unsigned short f2bf(float x){
  unsigned u; __builtin_memcpy(&u, &x, 4);
  u = (u + 0x7fffu + ((u >> 16) & 1u)) >> 16;
  return (unsigned short)u;
}
__device__ __forceinline__ float bf2f(unsigned short s){
  unsigned u = ((unsigned)s) << 16; float f; __builtin_memcpy(&f, &u, 4); return f;
}
__device__ __forceinline__ f32x4 mfma16(bf16x8 a, bf16x8 b, f32x4 c){
  return __builtin_amdgcn_mfma_f32_16x16x32_bf16(a, b, c, 0, 0, 0);
}

// ---------------- weight prep: fp32 -> bf16 in MFMA B-frag slice layout ----------------
// k-map for 16x16x32 bf16 MFMA operands: k = (j>>2)*16 + (lane>>4)*4 + (j&3)
__global__ __launch_bounds__(256) void prep_weights(
    const float* __restrict__ R1f, const float* __restrict__ W2f, const float* __restrict__ R2f,
    const float* __restrict__ R1b, const float* __restrict__ W2b, const float* __restrict__ R2b,
    unsigned short* __restrict__ dst)
{
  unsigned c = blockIdx.x * 256u + threadIdx.x;
  if (c >= 2359296u) return;
  unsigned reg, cc;
  if (c < 786432u)       { reg = 0; cc = c; }
  else if (c < 1572864u) { reg = 1; cc = c - 786432u; }
  else                   { reg = 2; cc = c - 1572864u; }
  unsigned dirq = cc / 393216u; unsigned r = cc % 393216u;
  const float* src; unsigned col, ktbase, kg4;
  if (reg < 2) {
    unsigned a = r / 6144u; r %= 6144u;
    unsigned g = r / 2048u; r %= 2048u;
    unsigned kt = r >> 6;  unsigned l = r & 63u;
    col = g*1024u + a*16u + (l & 15u);
    ktbase = kt*32u; kg4 = (l >> 4)*4u;
    src = (reg==0) ? (dirq ? R1b : R1f) : (dirq ? R2b : R2f);
  } else {
    unsigned s = r / 3072u; unsigned rr = r % 3072u;
    unsigned c0 = s * 24u;
    if (rr < 2048u) { unsigned kt = rr >> 6, l = rr & 63u; col = c0 + (l & 15u); ktbase = kt*32u; kg4 = (l>>4)*4u; }
    else { unsigned q = rr - 2048u; unsigned kt = q >> 5, sl = q & 31u; col = c0 + 16u + (sl & 7u); ktbase = kt*32u; kg4 = (sl >> 3)*4u; }
    src = dirq ? W2b : W2f;
  }
  unsigned short* d = dst + (size_t)c * 8u;
  #pragma unroll
  for (int j = 0; j < 8; ++j) {
    unsigned k = ktbase + ((j >> 2) << 4) + kg4 + (j & 3);
    d[j] = f2bf(src[(size_t)k * 3072u + col]);
  }
}

// ---------------- helpers ----------------
__device__ __forceinline__ void poll_ge(unsigned* base, int lane, int tgt, long* budget){
  if (tgt <= 0 || *budget <= 0) return;
  long it = 0;
  while (1) {
    unsigned v = __hip_atomic_load(base + lane, __ATOMIC_RELAXED, __HIP_MEMORY_SCOPE_AGENT);
    if (__all((int)v >= tgt)) return;
    if (++it > *budget) { *budget = 0; return; }   // safety valve: pipeline broken -> drain fast
    __builtin_amdgcn_s_sleep(1);
  }
}
__device__ __forceinline__ bf16x8 ld_frag(const char* slot, int kt, int mt, int lane){
  const uint64_t* p = (const uint64_t*)(slot + (((size_t)(kt*2 + mt)*64 + lane) << 4));
  union { uint64_t u[2]; bf16x8 v; } f;
  f.u[0] = __hip_atomic_load((uint64_t*)p,     __ATOMIC_RELAXED, __HIP_MEMORY_SCOPE_AGENT);
  f.u[1] = __hip_atomic_load((uint64_t*)p + 1, __ATOMIC_RELAXED, __HIP_MEMORY_SCOPE_AGENT);
  return f.v;
}
__device__ __forceinline__ void st16c(char* dst, const char* srcLDS){
  const uint64_t* s = (const uint64_t*)srcLDS;
  uint64_t a = s[0], b = s[1];
  __hip_atomic_store((uint64_t*)dst,     a, __ATOMIC_RELAXED, __HIP_MEMORY_SCOPE_AGENT);
  __hip_atomic_store((uint64_t*)dst + 1, b, __ATOMIC_RELAXED, __HIP_MEMORY_SCOPE_AGENT);
}

// ---------------- main persistent pipelined kernel ----------------
__global__ __launch_bounds__(256, 1) void enc_main(
    const int* __restrict__ tokens,
    const float* __restrict__ W1f, const float* __restrict__ W1b,
    const float* __restrict__ b1f, const float* __restrict__ b1b,
    const float* __restrict__ b2f, const float* __restrict__ b2b,
    char* __restrict__ ws, float* __restrict__ out)
{
  extern __shared__ char smem[];
  const int tid  = threadIdx.x;
  const int lane = tid & 63;
  const int wave = tid >> 6;
  const int mt   = wave >> 1;       // m-tile (batch 16-block) handled by this wave
  const int kh   = wave & 1;        // k-half (512) handled by this wave
  const int bid  = blockIdx.x;
  const int role = bid >> 6;        // 0 A_f, 1 C_f, 2 A_b, 3 C_b
  const int idx  = bid & 63;
  const int dir  = role >> 1;
  const int isC  = role & 1;
  const int u0   = idx * 16;        // owned unit base
  const int kt0  = u0 >> 5;         // k-tile our h-slice lands in
  const int uh8  = ((u0 >> 4) & 1) * 8;  // byte half within frag chunk
  const int i16  = lane & 15;
  const int lg   = lane >> 4;

  // stage weights into LDS
  {
    const size_t recoff = (isC ? R2L_OFF : R1L_OFF) + (size_t)(dir*64 + idx) * 98304;
    const uint4* rs = (const uint4*)(ws + recoff);
    uint4* rd = (uint4*)(smem + SM_RECW);
    #pragma unroll
    for (int i = 0; i < 24; ++i) rd[tid + 256*i] = rs[tid + 256*i];
    const size_t xoff = W2L_OFF + (size_t)(dir*128 + (isC ? 64 : 0) + idx) * 49152;
    const uint4* xs = (const uint4*)(ws + xoff);
    uint4* xd = (uint4*)(smem + SM_XW0);
    #pragma unroll
    for (int i = 0; i < 12; ++i) xd[tid + 256*i] = xs[tid + 256*i];
  }
  __syncthreads();

  unsigned* flags = (unsigned*)(ws + FLG_OFF);
  unsigned* fA1 = flags +   0 + dir*64;
  unsigned* fA2 = flags + 128 + dir*64;
  unsigned* fC1 = flags + 256 + dir*64;
  unsigned* fC2 = flags + 384 + dir*64;
  char* hr1 = ws + HR1_OFF + (size_t)dir * 16 * 65536;
  char* hr2 = ws + HR2_OFF + (size_t)dir * 16 * 65536;
  char* x2r = ws + X2R_OFF + (size_t)dir * 16 * 196608;
  const float* W1 = dir ? W1b : W1f;
  const float* b1 = dir ? b1b : b1f;
  const float* b2 = dir ? b2b : b2f;

  union FZ { uint64_t u[2]; bf16x8 v; };
  FZ fz; fz.u[0] = 0; fz.u[1] = 0;
  const bf16x8 zfrag = fz.v;

  long budget = 4000000;

  if (!isC) {
    // ---------------- stage A: layer-1 recurrence + 24 cols of x2 ----------------
    const int c0x = idx * 24;
    bf16x8 hfr[16];
    #pragma unroll
    for (int q = 0; q < 16; ++q) hfr[q] = zfrag;
    float hold[4] = {0.f, 0.f, 0.f, 0.f};
    float x1z[4], x1r[4], x1h[4];
    float b0z=0,b0r=0,b0h=0,brz=0,brr=0,brh=0;
    if (kh == 0) {
      b0z = b1[u0 + i16]; b0r = b1[1024 + u0 + i16]; b0h = b1[2048 + u0 + i16];
      brz = b1[3072 + u0 + i16]; brr = b1[4096 + u0 + i16]; brh = b1[5120 + u0 + i16];
      int tt = dir ? 511 : 0;
      #pragma unroll
      for (int r = 0; r < 4; ++r) {
        int m = mt*16 + lg*4 + r;
        int tok = tokens[m*512 + tt];
        const float* p = W1 + (size_t)tok*3072 + u0 + i16;
        x1z[r] = p[0]; x1r[r] = p[1024]; x1h[r] = p[2048];
      }
    }
    for (int t = 0; t < 512; ++t) {
      float nz[4], nr[4], nh[4];
      if (kh == 0 && t < 511) {                 // prefetch next embedding slice
        int tt = dir ? (510 - t) : (t + 1);
        #pragma unroll
        for (int r = 0; r < 4; ++r) {
          int m = mt*16 + lg*4 + r;
          int tok = tokens[m*512 + tt];
          const float* p = W1 + (size_t)tok*3072 + u0 + i16;
          nz[r] = p[0]; nr[r] = p[1024]; nh[r] = p[2048];
        }
      }
      f32x4 az = {0,0,0,0}, ar = {0,0,0,0}, ah = {0,0,0,0};
      #pragma unroll
      for (int q = 0; q < 16; ++q) {
        int kt = kh*16 + q;
        bf16x8 a = hfr[q];
        az = mfma16(a, *(const bf16x8*)(smem + SM_RECW +         (kt<<10) + (lane<<4)), az);
        ar = mfma16(a, *(const bf16x8*)(smem + SM_RECW + 32768 + (kt<<10) + (lane<<4)), ar);
        ah = mfma16(a, *(const bf16x8*)(smem + SM_RECW + 65536 + (kt<<10) + (lane<<4)), ah);
      }
      __syncthreads();
      if (kh == 1) {
        f32x4* red = (f32x4*)(smem + (mt ? SM_RED1 : SM_RED0));
        red[lane] = az; red[64 + lane] = ar; red[128 + lane] = ah;
      }
      __syncthreads();
      if (kh == 0) {
        const f32x4* red = (const f32x4*)(smem + (mt ? SM_RED1 : SM_RED0));
        f32x4 rz = red[lane], rr4 = red[64 + lane], rh = red[128 + lane];
        #pragma unroll
        for (int r = 0; r < 4; ++r) {
          float zp = x1z[r] + b0z + az[r] + rz[r] + brz;
          float rp = x1r[r] + b0r + ar[r] + rr4[r] + brr;
          float zg = 1.f / (1.f + __expf(-zp));
          float rg = 1.f / (1.f + __expf(-rp));
          float hp = (x1h[r] + b0h) + rg * (ah[r] + rh[r] + brh);
          float e2 = __expf(-2.f * hp);
          float th = (1.f - e2) / (1.f + e2);
          float hn = zg * hold[r] + (1.f - zg) * th;
          hold[r] = hn;
          *(unsigned short*)(smem + SM_HST + ((mt*16 + lg*4 + r)*16 + i16)*2) = f2bf(hn);
        }
        if (t == 511) {
          #pragma unroll
          for (int r = 0; r < 4; ++r)
            out[YSZ + (size_t)dir*65536 + (size_t)(mt*16 + lg*4 + r)*2048 + u0 + i16] = hold[r];
        }
      }
      __syncthreads();
      char* h1slot = hr1 + (size_t)(t & 15) * 65536;
      if (wave == 0) {
        poll_ge(fC1, lane, t - 15, &budget);    // ring back-pressure
        #pragma unroll
        for (int mtl = 0; mtl < 2; ++mtl) {     // publish h1[t] slice (8B halves, frag layout)
          uint64_t v = *(const uint64_t*)(smem + SM_HST + (mtl*256 + (lane & 15)*16 + ((lane >> 4) << 2))*2);
          __hip_atomic_store((uint64_t*)(h1slot + (((size_t)(kt0*2 + mtl)*64 + lane) << 4) + uh8),
                             v, __ATOMIC_RELAXED, __HIP_MEMORY_SCOPE_AGENT);
        }
        if (lane == 0)
          __hip_atomic_store(fA1 + idx, (unsigned)(t + 1), __ATOMIC_RELEASE, __HIP_MEMORY_SCOPE_AGENT);
        poll_ge(fA1, lane, t + 1, &budget);     // wait full h1[t]
      }
      __syncthreads();
      #pragma unroll
      for (int q = 0; q < 16; ++q) hfr[q] = ld_frag(h1slot, kh*16 + q, mt, lane);  // reused next step
      f32x4 a0 = {0,0,0,0}, a1 = {0,0,0,0};
      #pragma unroll
      for (int q = 0; q < 16; ++q) {
        int kt = kh*16 + q;
        bf16x8 a = hfr[q];
        a0 = mfma16(a, *(const bf16x8*)(smem + SM_XW0 + (kt<<10) + (lane<<4)), a0);
        bf16x8 bb = zfrag;
        if (i16 < 8) bb = *(const bf16x8*)(smem + SM_XW1 + (kt<<9) + ((lg*8 + (lane & 7)) << 4));
        a1 = mfma16(a, bb, a1);
      }
      __syncthreads();
      if (kh == 1) {
        f32x4* red = (f32x4*)(smem + (mt ? SM_RED1 : SM_RED0));
        red[lane] = a0; red[64 + lane] = a1;
      }
      __syncthreads();
      if (kh == 0) {
        const f32x4* red = (const f32x4*)(smem + (mt ? SM_RED1 : SM_RED0));
        f32x4 r0 = red[lane], r1 = red[64 + lane];
        #pragma unroll
        for (int r = 0; r < 4; ++r) {
          int m = mt*16 + lg*4 + r;
          *(unsigned short*)(smem + SM_XST + (i16*32 + m)*2) = f2bf(a0[r] + r0[r]);
          if (i16 < 8)
            *(unsigned short*)(smem + SM_XST + ((16 + i16)*32 + m)*2) = f2bf(a1[r] + r1[r]);
        }
      }
      __syncthreads();
      if (wave == 0) {
        char* xslot = x2r + (size_t)(t & 15) * 196608;
        st16c(xslot + (size_t)(c0x + (lane >> 2))*64 + (lane & 3)*16,
              smem + SM_XST + (lane >> 2)*64 + (lane & 3)*16);
        if (lane < 32) {
          int c = 64 + lane;
          st16c(xslot + (size_t)(c0x + (c >> 2))*64 + (c & 3)*16,
                smem + SM_XST + (c >> 2)*64 + (c & 3)*16);
        }
        if (lane == 0)
          __hip_atomic_store(fA2 + idx, (unsigned)(t + 1), __ATOMIC_RELEASE, __HIP_MEMORY_SCOPE_AGENT);
      }
      if (kh == 0 && t < 511) {
        #pragma unroll
        for (int r = 0; r < 4; ++r) { x1z[r] = nz[r]; x1r[r] = nr[r]; x1h[r] = nh[r]; }
      }
    }
  } else {
    // ---------------- stage C: layer-2 recurrence + 24 cols of x2 + output ----------------
    const int c0x = 1536 + idx * 24;
    bf16x8 hf2[16], hf1[16];
    #pragma unroll
    for (int q = 0; q < 16; ++q) { hf2[q] = zfrag; hf1[q] = zfrag; }
    float hold[4] = {0.f, 0.f, 0.f, 0.f};
    float b0z=0,b0r=0,b0h=0,brz=0,brr=0,brh=0;
    if (kh == 0) {
      b0z = b2[u0 + i16]; b0r = b2[1024 + u0 + i16]; b0h = b2[2048 + u0 + i16];
      brz = b2[3072 + u0 + i16]; brr = b2[4096 + u0 + i16]; brh = b2[5120 + u0 + i16];
    }
    for (int t = 0; t < 512; ++t) {
      if (wave == 0 && t > 0) poll_ge(fC1, lane, t, &budget);
      __syncthreads();
      if (t > 0) {
        char* h2slot = hr2 + (size_t)((t - 1) & 15) * 65536;
        #pragma unroll
        for (int q = 0; q < 16; ++q) hf2[q] = ld_frag(h2slot, kh*16 + q, mt, lane);
      }
      f32x4 az = {0,0,0,0}, ar = {0,0,0,0}, ah = {0,0,0,0};
      #pragma unroll
      for (int q = 0; q < 16; ++q) {
        int kt = kh*16 + q;
        bf16x8 a = hf2[q];
        az = mfma16(a, *(const bf16x8*)(smem + SM_RECW +         (kt<<10) + (lane<<4)), az);
        ar = mfma16(a, *(const bf16x8*)(smem + SM_RECW + 32768 + (kt<<10) + (lane<<4)), ar);
        ah = mfma16(a, *(const bf16x8*)(smem + SM_RECW + 65536 + (kt<<10) + (lane<<4)), ah);
      }
      __syncthreads();
      if (kh == 1) {
        f32x4* red = (f32x4*)(smem + (mt ? SM_RED1 : SM_RED0));
        red[lane] = az; red[64 + lane] = ar; red[128 + lane] = ah;
      }
      __syncthreads();
      f32x4 rz = {0,0,0,0}, rr4 = {0,0,0,0}, rh = {0,0,0,0};
      if (kh == 0) {
        const f32x4* red = (const f32x4*)(smem + (mt ? SM_RED1 : SM_RED0));
        rz = red[lane]; rr4 = red[64 + lane]; rh = red[128 + lane];
      }
      if (wave == 0) poll_ge(fA1, lane, t + 1, &budget);    // wait h1[t]
      __syncthreads();
      char* h1slot = hr1 + (size_t)(t & 15) * 65536;
      #pragma unroll
      for (int q = 0; q < 16; ++q) hf1[q] = ld_frag(h1slot, kh*16 + q, mt, lane);
      f32x4 a0 = {0,0,0,0}, a1 = {0,0,0,0};
      #pragma unroll
      for (int q = 0; q < 16; ++q) {
        int kt = kh*16 + q;
        bf16x8 a = hf1[q];
        a0 = mfma16(a, *(const bf16x8*)(smem + SM_XW0 + (kt<<10) + (lane<<4)), a0);
        bf16x8 bb = zfrag;
        if (i16 < 8) bb = *(const bf16x8*)(smem + SM_XW1 + (kt<<9) + ((lg*8 + (lane & 7)) << 4));
        a1 = mfma16(a, bb, a1);
      }
      __syncthreads();
      if (kh == 1) {
        f32x4* red = (f32x4*)(smem + (mt ? SM_RED1 : SM_RED0));
        red[lane] = a0; red[64 + lane] = a1;
      }
      __syncthreads();
      if (kh == 0) {
        const f32x4* red = (const f32x4*)(smem + (mt ? SM_RED1 : SM_RED0));
        f32x4 r0 = red[lane], r1 = red[64 + lane];
        #pragma unroll
        for (int r = 0; r < 4; ++r) {
          int m = mt*16 + lg*4 + r;
          *(unsigned short*)(smem + SM_XST + (i16*32 + m)*2) = f2bf(a0[r] + r0[r]);
          if (i16 < 8)
            *(unsigned short*)(smem + SM_XST + ((16 + i16)*32 + m)*2) = f2bf(a1[r] + r1[r]);
        }
      }
      __syncthreads();
      char* xslot = x2r + (size_t)(t & 15) * 196608;
      if (wave == 0) {
        st16c(xslot + (size_t)(c0x + (lane >> 2))*64 + (lane & 3)*16,
              smem + SM_XST + (lane >> 2)*64 + (lane & 3)*16);
        if (lane < 32) {
          int c = 64 + lane;
          st16c(xslot + (size_t)(c0x + (c >> 2))*64 + (c & 3)*16,
                smem + SM_XST + (c >> 2)*64 + (c & 3)*16);
        }
        if (lane == 0)
          __hip_atomic_store(fC2 + idx, (unsigned)(t + 1), __ATOMIC_RELEASE, __HIP_MEMORY_SCOPE_AGENT);
        poll_ge(fA2, lane, t + 1, &budget);
        poll_ge(fC2, lane, t + 1, &budget);
      }
      __syncthreads();
      if (kh == 0) {
        int m0 = mt*16 + lg*4;
        float xg[3][4];
        #pragma unroll
        for (int g = 0; g < 3; ++g) {
          uint64_t v = __hip_atomic_load(
              (uint64_t*)(xslot + ((size_t)(g*1024 + u0 + i16)*32 + m0)*2),
              __ATOMIC_RELAXED, __HIP_MEMORY_SCOPE_AGENT);
          #pragma unroll
          for (int r = 0; r < 4; ++r) xg[g][r] = bf2f((unsigned short)(v >> (16*r)));
        }
        int tt = dir ? (511 - t) : t;
        #pragma unroll
        for (int r = 0; r < 4; ++r) {
          float zp = xg[0][r] + b0z + az[r] + rz[r] + brz;
          float rp = xg[1][r] + b0r + ar[r] + rr4[r] + brr;
          float zg = 1.f / (1.f + __expf(-zp));
          float rg = 1.f / (1.f + __expf(-rp));
          float hp = (xg[2][r] + b0h) + rg * (ah[r] + rh[r] + brh);
          float e2 = __expf(-2.f * hp);
          float th = (1.f - e2) / (1.f + e2);
          float hn = zg * hold[r] + (1.f - zg) * th;
          hold[r] = hn;
          *(unsigned short*)(smem + SM_HST + ((mt*16 + lg*4 + r)*16 + i16)*2) = f2bf(hn);
          int m = m0 + r;
          out[((size_t)m*512 + tt)*2048 + dir*1024 + u0 + i16] = hn;
          if (t == 511)
            out[YSZ + (size_t)dir*65536 + (size_t)m*2048 + 1024 + u0 + i16] = hn;
        }
      }
      __syncthreads();
      if (wave == 0) {
        char* h2slot = hr2 + (size_t)(t & 15) * 65536;
        #pragma unroll
        for (int mtl = 0; mtl < 2; ++mtl) {
          uint64_t v = *(const uint64_t*)(smem + SM_HST + (mtl*256 + (lane & 15)*16 + ((lane >> 4) << 2))*2);
          __hip_atomic_store((uint64_t*)(h2slot + (((size_t)(kt0*2 + mtl)*64 + lane) << 4) + uh8),
                             v, __ATOMIC_RELAXED, __HIP_MEMORY_SCOPE_AGENT);
        }
        if (lane == 0)
          __hip_atomic_store(fC1 + idx, (unsigned)(t + 1), __ATOMIC_RELEASE, __HIP_MEMORY_SCOPE_AGENT);
      }
    }
  }
}

extern "C" void kernel_launch(void* const* d_in, const int* in_sizes, int n_in,
                              void* d_out, int out_size, void* d_ws, size_t ws_size,
                              hipStream_t stream)
{
  const int*   tokens = (const int*)d_in[0];
  const float* W1f = (const float*)d_in[1];
  const float* R1f = (const float*)d_in[2];
  const float* b1f = (const float*)d_in[3];
  const float* W2f = (const float*)d_in[4];
  const float* R2f = (const float*)d_in[5];
  const float* b2f = (const float*)d_in[6];
  const float* W1b = (const float*)d_in[7];
  const float* R1b = (const float*)d_in[8];
  const float* b1b = (const float*)d_in[9];
  const float* W2b = (const float*)d_in[10];
  const float* R2b = (const float*)d_in[11];
  const float* b2b = (const float*)d_in[12];
  char* ws = (char*)d_ws;
  (void)in_sizes; (void)n_in; (void)out_size;
  if (ws_size < WS_NEED) return;

  hipMemsetAsync(ws + FLG_OFF, 0, 4096, stream);
  prep_weights<<<9216, 256, 0, stream>>>(R1f, W2f, R2f, R1b, W2b, R2b, (unsigned short*)ws);
  hipFuncSetAttribute((const void*)enc_main, hipFuncAttributeMaxDynamicSharedMemorySize, 163840);
  enc_main<<<256, 256, SM_BYTES, stream>>>(tokens, W1f, W1b, b1f, b1b, b2f, b2b, ws, (float*)d_out);
}